// Round 8
// baseline (335.665 us; speedup 1.0000x reference)
//
#include <hip/hip_runtime.h>
#include <math.h>

#define NB 4096
#define NN 64

typedef _Float16 h8 __attribute__((ext_vector_type(8)));
typedef float f4 __attribute__((ext_vector_type(4)));
typedef unsigned long long u64;

typedef const __attribute__((address_space(1))) void* gas_t;
typedef __attribute__((address_space(3))) void* las_t;

__device__ __forceinline__ void gload16(const void* g, void* l) {
  __builtin_amdgcn_global_load_lds((gas_t)g, (las_t)l, 16, 0, 0);
}
__device__ __forceinline__ void rbar() {
  asm volatile("" ::: "memory");
  __builtin_amdgcn_s_barrier();
  asm volatile("" ::: "memory");
}
__device__ __forceinline__ void lgkm0() {
  asm volatile("s_waitcnt lgkmcnt(0)" ::: "memory");
}
template<int N> __device__ __forceinline__ void waitv() {
  if constexpr (N == 0)       asm volatile("s_waitcnt vmcnt(0)" ::: "memory");
  else if constexpr (N == 1)  asm volatile("s_waitcnt vmcnt(1)" ::: "memory");
  else if constexpr (N == 9)  asm volatile("s_waitcnt vmcnt(9)" ::: "memory");
  else if constexpr (N == 25) asm volatile("s_waitcnt vmcnt(25)" ::: "memory");
  else                        asm volatile("s_waitcnt vmcnt(27)" ::: "memory");
  __builtin_amdgcn_sched_barrier(0);
}

// G act buffers: 64 rows x 128 f16, 256 B stride, byte ^= (row&7)<<4
__device__ __forceinline__ int aoff(int row, int colb) {
  return row * 256 + (colb ^ ((row & 7) << 4));
}
__device__ __forceinline__ h8 ald8(const char* a, int row, int colb) {
  return *(const h8*)(a + aoff(row, colb));
}
__device__ __forceinline__ void ast8(char* a, int row, int colb, h8 v) {
  *(h8*)(a + aoff(row, colb)) = v;
}
__device__ __forceinline__ _Float16 ald(const char* a, int row, int colb) {
  return *(const _Float16*)(a + aoff(row, colb));
}
__device__ __forceinline__ void ast(char* a, int row, int colb, _Float16 v) {
  *(_Float16*)(a + aoff(row, colb)) = v;
}
// S scratch: 64 rows x 64 f16, 128 B stride, same XOR
__device__ __forceinline__ int soff(int row, int colb) {
  return row * 128 + (colb ^ ((row & 7) << 4));
}
__device__ __forceinline__ h8 sld8(const char* s, int row, int colb) {
  return *(const h8*)(s + soff(row, colb));
}
__device__ __forceinline__ void sst(char* s, int row, int colb, _Float16 v) {
  *(_Float16*)(s + soff(row, colb)) = v;
}

// ---------------- weight prep ----------------
// f16 ws layout: 0 Wl1p[128][32] | 4096 Wl2p[32][128] | 8192 W11p[128][32] |
// 12288 W12 | 28672 W21 | 45056 W22 | 61440 Wat 2x[128][128] (= (Wo.Wv)) |
// 94208 Wf1 2x | 126976 Wf2 2x | 159744: f32 bat[2][128]
__global__ void prepA(
    const float* __restrict__ W_l1, const float* __restrict__ W_l2,
    const float* __restrict__ W11, const float* __restrict__ W12,
    const float* __restrict__ W21, const float* __restrict__ W22,
    const float* __restrict__ Wf1, const float* __restrict__ Wf2,
    _Float16* __restrict__ ws)
{
  const int e = blockIdx.x * 256 + threadIdx.x;
  float v;
  if (e < 4096) { const int o = e >> 5, k = e & 31; v = (k < 20) ? W_l1[o * 20 + k] : 0.f; }
  else if (e < 8192) { const int i = e - 4096; const int o = i >> 7, k = i & 127; v = (o < 20) ? W_l2[o * 128 + k] : 0.f; }
  else if (e < 12288) { const int i = e - 8192; const int o = i >> 5, k = i & 31; v = (k < 27) ? W11[o * 27 + k] : 0.f; }
  else if (e < 28672) v = W12[e - 12288];
  else if (e < 45056) v = W21[e - 28672];
  else if (e < 61440) v = W22[e - 45056];
  else if (e < 94208) return;                      // Wat by prepB
  else if (e < 126976) v = Wf1[e - 94208];
  else v = Wf2[e - 126976];
  ws[e] = (_Float16)v;
}

__global__ void prepB(
    const float* __restrict__ Wqkv, const float* __restrict__ bqkv,
    const float* __restrict__ Wo, const float* __restrict__ bo,
    _Float16* __restrict__ ws)
{
  if (blockIdx.x < 128) {
    const int e = blockIdx.x * 256 + threadIdx.x;       // 0..32767
    const int l = e >> 14, r = e & 16383, o = r >> 7, k = r & 127;
    const float* wo = Wo + (l * 128 + o) * 128;
    const float* wv = Wqkv + l * 49152 + 32768 + k;
    float acc = 0.f;
#pragma unroll 4
    for (int m = 0; m < 128; ++m) acc += wo[m] * wv[m * 128];
    ws[61440 + e] = (_Float16)acc;
  } else {
    const int t = threadIdx.x;                          // 0..255
    const int l = t >> 7, o = t & 127;
    const float* wo = Wo + (l * 128 + o) * 128;
    const float* bv = bqkv + l * 384 + 256;
    float acc = bo[l * 128 + o];
    for (int m = 0; m < 128; ++m) acc += bv[m] * wo[m];
    ((float*)(ws + 159744))[l * 128 + o] = acc;
  }
}

// ---------------- chunk staging (4 KB, pre-swizzled source) ----------------
__device__ __forceinline__ void stage64(const _Float16* __restrict__ Wp, int KT,
                                        int kc, int oc, char* buf, int tid) {
  const int o = tid >> 2, kq = tid & 3;
  const int kreal = kq ^ ((o >> 1) & 3);
  gload16(Wp + (oc * 64 + o) * KT + kc * 32 + kreal * 8, buf + tid * 16);
}
__device__ __forceinline__ void stage32(const _Float16* __restrict__ Wp,
                                        int kc, char* buf, int tid) {
  const int o = tid >> 3, u = tid & 7;
  const int ureal = u ^ (o & 7);
  gload16(Wp + o * 128 + kc * 64 + ureal * 8, buf + tid * 16);
}

// ---------------- in-place matmul, both graphs ----------------
// D_g = act(src_g x W^T + b (+resid=G)) written back into G_g (same rows).
// af0/af1 preloaded by caller (KT/32 frags). Chunks (kc=q>>1, oc=q&1).
template<int KT, bool RELU, bool RESID, bool CONT, int W0, typename PF>
__device__ __forceinline__ void mm_run(
    const _Float16* __restrict__ Wp, const float* bv8,
    const h8* af0, const h8* af1,
    char* d0, char* d1, char* wbase, int& wbi, int tid, PF&& pf)
{
  constexpr int NK = KT / 32, NCH = 2 * NK;
  const int lane = tid & 63, wv = tid >> 6, lc = lane & 15, kg = lane >> 4;
  f4 acc0[8], acc1[8];
#pragma unroll
  for (int t = 0; t < 8; ++t) { acc0[t] = (f4){0.f,0.f,0.f,0.f}; acc1[t] = (f4){0.f,0.f,0.f,0.f}; }
#pragma unroll
  for (int q = 0; q < NCH; ++q) {
    if (q < 2) waitv<W0>();
    else if (!CONT && q == NCH - 1) waitv<0>();
    else waitv<1>();
    rbar();
    if (q + 2 < NCH) stage64(Wp, KT, (q + 2) >> 1, (q + 2) & 1,
                             wbase + ((wbi + q + 2) % 3) * 4096, tid);
    else pf(q + 2 - NCH, (wbi + q + 2) % 3);
    const char* wb = wbase + ((wbi + q) % 3) * 4096;
    const int kc = q >> 1, oc = q & 1;
    h8 bf[4];
#pragma unroll
    for (int t = 0; t < 4; ++t) {
      const int o = t * 16 + lc;
      const int kq = kg ^ ((o >> 1) & 3);
      bf[t] = *(const h8*)(wb + (o * 4 + kq) * 16);
    }
#pragma unroll
    for (int t = 0; t < 4; ++t)
      acc0[oc * 4 + t] = __builtin_amdgcn_mfma_f32_16x16x32_f16(af0[kc], bf[t], acc0[oc * 4 + t], 0, 0, 0);
#pragma unroll
    for (int t = 0; t < 4; ++t)
      acc1[oc * 4 + t] = __builtin_amdgcn_mfma_f32_16x16x32_f16(af1[kc], bf[t], acc1[oc * 4 + t], 0, 0, 0);
  }
  wbi = (wbi + NCH) % 3;
  const int rbase = wv * 16 + kg * 4;
#pragma unroll
  for (int t = 0; t < 8; ++t) {
    const int col = t * 16 + lc;
    const float bvv = bv8[t];
#pragma unroll
    for (int r = 0; r < 4; ++r) {
      float v0 = acc0[t][r] + bvv, v1 = acc1[t][r] + bvv;
      if constexpr (RESID) {
        v0 += (float)ald(d0, rbase + r, col * 2);
        v1 += (float)ald(d1, rbase + r, col * 2);
      }
      if constexpr (RELU) { v0 = fmaxf(v0, 0.f); v1 = fmaxf(v1, 0.f); }
      ast(d0, rbase + r, col * 2, (_Float16)v0);
      ast(d1, rbase + r, col * 2, (_Float16)v1);
    }
  }
}

// lidar2: O=32 (20 used), K=128, dst = XC cols 7..26 of G (in-place)
template<int W0, typename PF>
__device__ __forceinline__ void mm32_run(
    const _Float16* __restrict__ Wp, const float* bv2,
    const h8* af0, const h8* af1,
    char* d0, char* d1, char* wbase, int& wbi, int tid, PF&& pf)
{
  const int lane = tid & 63, wv = tid >> 6, lc = lane & 15, kg = lane >> 4;
  f4 a0[2], a1[2];
  a0[0] = a0[1] = a1[0] = a1[1] = (f4){0.f,0.f,0.f,0.f};
#pragma unroll
  for (int q = 0; q < 2; ++q) {
    waitv<W0>();
    rbar();
    pf(q, (wbi + q + 2) % 3);
    const char* wb = wbase + ((wbi + q) % 3) * 4096;
#pragma unroll
    for (int ks = 0; ks < 2; ++ks) {
      h8 bf[2];
#pragma unroll
      for (int t = 0; t < 2; ++t) {
        const int o = t * 16 + lc;
        const int u = (ks * 4 + kg) ^ (o & 7);
        bf[t] = *(const h8*)(wb + (o * 8 + u) * 16);
      }
#pragma unroll
      for (int t = 0; t < 2; ++t) {
        a0[t] = __builtin_amdgcn_mfma_f32_16x16x32_f16(af0[q * 2 + ks], bf[t], a0[t], 0, 0, 0);
        a1[t] = __builtin_amdgcn_mfma_f32_16x16x32_f16(af1[q * 2 + ks], bf[t], a1[t], 0, 0, 0);
      }
    }
  }
  wbi = (wbi + 2) % 3;
  const int rbase = wv * 16 + kg * 4;
#pragma unroll
  for (int t = 0; t < 2; ++t) {
    const int col = t * 16 + lc;
    if (col < 20) {
      const float bvv = bv2[t];
#pragma unroll
      for (int r = 0; r < 4; ++r) {
        ast(d0, rbase + r, 78 + col * 2, (_Float16)fmaxf(a0[t][r] + bvv, 0.f));
        ast(d1, rbase + r, 78 + col * 2, (_Float16)fmaxf(a1[t][r] + bvv, 0.f));
      }
    }
  }
}

// ---------------- S-routed producer family (lidar1 / Wf1) ----------------
// 4 sub-phases (oc,g): half out-cols of one graph -> S, relu+bias; then the
// consumer A-frags afd_g[oc*2+j] are loaded from S before S is reused.
template<int KT, int W0, typename PF>
__device__ __forceinline__ void s_family(
    const _Float16* __restrict__ Wp, const float* bv8,
    const h8* afs0, const h8* afs1,
    h8* afd0, h8* afd1,
    char* S, char* wbase, int& wbi, int tid, PF&& pf)
{
  constexpr int KCH = KT / 32, NST = 4 * KCH;
  const int lane = tid & 63, wv = tid >> 6, lc = lane & 15, kg = lane >> 4;
  const int row0 = wv * 16 + lc;
  int step = 0;
#pragma unroll
  for (int p = 0; p < 4; ++p) {
    const int oc = p >> 1, g = p & 1;
    const h8* af = g ? afs1 : afs0;
    f4 acc[4];
#pragma unroll
    for (int t = 0; t < 4; ++t) acc[t] = (f4){0.f,0.f,0.f,0.f};
#pragma unroll
    for (int kc = 0; kc < KCH; ++kc, ++step) {
      if (step < 2) waitv<W0>(); else waitv<1>();
      rbar();
      const int nx = step + 2;
      if (nx < NST) stage64(Wp, KT, nx % KCH, (nx / KCH) >> 1,
                            wbase + ((wbi + nx) % 3) * 4096, tid);
      else pf(nx - NST, (wbi + nx) % 3);
      const char* wb = wbase + ((wbi + step) % 3) * 4096;
      h8 bf[4];
#pragma unroll
      for (int t = 0; t < 4; ++t) {
        const int o = t * 16 + lc;
        const int kq = kg ^ ((o >> 1) & 3);
        bf[t] = *(const h8*)(wb + (o * 4 + kq) * 16);
      }
#pragma unroll
      for (int t = 0; t < 4; ++t)
        acc[t] = __builtin_amdgcn_mfma_f32_16x16x32_f16(af[kc], bf[t], acc[t], 0, 0, 0);
    }
    const int rbase = wv * 16 + kg * 4;
#pragma unroll
    for (int t = 0; t < 4; ++t) {
      const int col = t * 16 + lc;
      const float bvv = bv8[oc * 4 + t];
#pragma unroll
      for (int r = 0; r < 4; ++r)
        sst(S, rbase + r, col * 2, (_Float16)fmaxf(acc[t][r] + bvv, 0.f));
    }
    lgkm0(); rbar();
    h8* afd = g ? afd1 : afd0;
    afd[oc * 2 + 0] = sld8(S, row0, kg * 16);
    afd[oc * 2 + 1] = sld8(S, row0, 64 + kg * 16);
    lgkm0();
  }
  wbi = (wbi + NST) % 3;
}

// agg128 half: S <- (M'+... = mcol bits incl diag)^T x Gg, cols oc*64..+63
__device__ __forceinline__ void agg128_half(
    const u64* mcolg, const char* Gg, char* S, int oc, int tid)
{
  const int lane = tid & 63, wv = tid >> 6, lc = lane & 15, kg = lane >> 4;
  const int cl = wv * 16 + lc;
  u64 mrow[4];
#pragma unroll
  for (int rt = 0; rt < 4; ++rt) mrow[rt] = mcolg[rt * 16 + lc];
  f4 acc[4];
#pragma unroll
  for (int rt = 0; rt < 4; ++rt) acc[rt] = (f4){0.f,0.f,0.f,0.f};
#pragma unroll
  for (int ks = 0; ks < 2; ++ks) {
    h8 bf;
#pragma unroll
    for (int e = 0; e < 8; ++e) bf[e] = ald(Gg, ks * 32 + kg * 8 + e, (oc * 64 + cl) * 2);
#pragma unroll
    for (int rt = 0; rt < 4; ++rt) {
      const unsigned int byte = (unsigned int)(mrow[rt] >> (ks * 32 + kg * 8)) & 0xffu;
      h8 af;
#pragma unroll
      for (int e = 0; e < 8; ++e) af[e] = (_Float16)((byte >> e) & 1u);
      acc[rt] = __builtin_amdgcn_mfma_f32_16x16x32_f16(af, bf, acc[rt], 0, 0, 0);
    }
  }
#pragma unroll
  for (int rt = 0; rt < 4; ++rt)
#pragma unroll
    for (int qq = 0; qq < 4; ++qq)
      sst(S, rt * 16 + kg * 4 + qq, cl * 2, (_Float16)acc[rt][qq]);
}

// agg32: in-place G, waves 0-1 g0, 2-3 g1; reads XC (colb 64+), writes cols 0..31
__device__ __forceinline__ void agg32_2g(
    const u64* mc0, const u64* mc1, char* g0buf, char* g1buf, int tid)
{
  const int lane = tid & 63, wv = tid >> 6, lc = lane & 15, kg = lane >> 4;
  const int g = wv >> 1;
  const u64* mc = g ? mc1 : mc0;
  char* buf = g ? g1buf : g0buf;
  const int c0 = (wv & 1) * 16 + lc;
  u64 mrow[4];
#pragma unroll
  for (int rt = 0; rt < 4; ++rt) mrow[rt] = mc[rt * 16 + lc];
  f4 acc[4];
#pragma unroll
  for (int rt = 0; rt < 4; ++rt) acc[rt] = (f4){0.f,0.f,0.f,0.f};
#pragma unroll
  for (int ks = 0; ks < 2; ++ks) {
    h8 bf;
#pragma unroll
    for (int e = 0; e < 8; ++e) bf[e] = ald(buf, ks * 32 + kg * 8 + e, 64 + c0 * 2);
#pragma unroll
    for (int rt = 0; rt < 4; ++rt) {
      const unsigned int byte = (unsigned int)(mrow[rt] >> (ks * 32 + kg * 8)) & 0xffu;
      h8 af;
#pragma unroll
      for (int e = 0; e < 8; ++e) af[e] = (_Float16)((byte >> e) & 1u);
      acc[rt] = __builtin_amdgcn_mfma_f32_16x16x32_f16(af, bf, acc[rt], 0, 0, 0);
    }
  }
#pragma unroll
  for (int rt = 0; rt < 4; ++rt)
#pragma unroll
    for (int qq = 0; qq < 4; ++qq)
      ast(buf, rt * 16 + kg * 4 + qq, c0 * 2, (_Float16)acc[rt][qq]);
}

// in-place LN with preloaded params (float4 regs)
__device__ __forceinline__ void layer_norm(
    char* buf, const float4* lg, const float4* lb, int tid)
{
  const int n = tid >> 2, q = tid & 3;
  float vals[32];
#pragma unroll
  for (int u = 0; u < 4; ++u) {
    const h8 v = ald8(buf, n, q * 64 + u * 16);
#pragma unroll
    for (int e = 0; e < 8; ++e) vals[u * 8 + e] = (float)v[e];
  }
  float s = 0.f;
#pragma unroll
  for (int u = 0; u < 32; ++u) s += vals[u];
  s += __shfl_xor(s, 1, 64);
  s += __shfl_xor(s, 2, 64);
  const float mean = s * 0.0078125f;
  float vv = 0.f;
#pragma unroll
  for (int u = 0; u < 32; ++u) { const float d = vals[u] - mean; vv = fmaf(d, d, vv); }
  vv += __shfl_xor(vv, 1, 64);
  vv += __shfl_xor(vv, 2, 64);
  const float rstd = 1.0f / sqrtf(vv * 0.0078125f + 1e-5f);
#pragma unroll
  for (int u = 0; u < 4; ++u) {
    h8 o;
#pragma unroll
    for (int e = 0; e < 8; ++e) {
      const float gg = ((const float*)&lg[u * 2 + (e >> 2)])[e & 3];
      const float bb = ((const float*)&lb[u * 2 + (e >> 2)])[e & 3];
      o[e] = (_Float16)((vals[u * 8 + e] - mean) * rstd * gg + bb);
    }
    ast8(buf, n, q * 64 + u * 16, o);
  }
}

struct SM {
  alignas(16) char G0[16384];
  alignas(16) char G1[16384];
  alignas(16) char S[8192];
  alignas(16) char WB[12288];
  u64 mcol[2][64];
};   // 54272 B -> 3 blocks/CU

__global__ __launch_bounds__(256, 3)
void gin_critic_kernel(
    const float* __restrict__ data,
    const float* __restrict__ b_l1, const float* __restrict__ b_l2,
    const float* __restrict__ b11, const float* __restrict__ b12,
    const float* __restrict__ b21, const float* __restrict__ b22,
    const float* __restrict__ ln1_g, const float* __restrict__ ln1_b,
    const float* __restrict__ bf1, const float* __restrict__ bf2,
    const float* __restrict__ ln2_g, const float* __restrict__ ln2_b,
    const float* __restrict__ Wfc, const float* __restrict__ bfc,
    const _Float16* __restrict__ ws,
    float* __restrict__ out)
{
  __shared__ SM sm;
  const int tid = threadIdx.x;
  const int lane = tid & 63, wv = tid >> 6, lc = lane & 15, kg = lane >> 4;
  const int row0 = wv * 16 + lc;
  const int b = blockIdx.x;
  const long base = (long)b * 2 * NN * 27;
  char* G0 = sm.G0; char* G1 = sm.G1; char* S = sm.S; char* wbase = sm.WB;
  int wbi = 0;

  const _Float16* Wl1p = ws + 0;
  const _Float16* Wl2p = ws + 4096;
  const _Float16* W11p = ws + 8192;
  const _Float16* W12p = ws + 12288;
  const _Float16* W21p = ws + 28672;
  const _Float16* W22p = ws + 45056;
  const _Float16* Wat0 = ws + 61440;
  const _Float16* Wat1 = ws + 61440 + 16384;
  const _Float16* Wf1_0 = ws + 94208;
  const _Float16* Wf1_1 = ws + 94208 + 16384;
  const _Float16* Wf2_0 = ws + 126976;
  const _Float16* Wf2_1 = ws + 126976 + 16384;
  const float* batp = (const float*)(ws + 159744);

  // ---- prologue: lidar1 chunk0,1 in flight (both = oc0 content) ----
  stage64(Wl1p, 32, 0, 0, wbase + 0 * 4096, tid);
  stage64(Wl1p, 32, 0, 0, wbase + 1 * 4096, tid);
  __builtin_amdgcn_sched_barrier(0);

  // ---- input staging: exactly 14 uniform global loads per thread ----
#pragma unroll
  for (int i = 0; i < 14; ++i) {
    const int idx = tid + i * 256;
    const int cidx = idx < 3456 ? idx : 3455;
    float v = data[base + cidx];
    asm volatile("" : "+v"(v));                 // keep load unconditional
    if (idx < 3456) {
      const int gi = idx / 1728;
      const int r = idx - gi * 1728;
      const int n = r / 27, f = r - n * 27;
      char* Gg = gi ? G1 : G0;
      if (f < 7) ast(Gg, n, 64 + f * 2, (_Float16)v);
      else       ast(Gg, n, (f - 7) * 2, (_Float16)v);
    }
  }
  if (tid < 128) {
    const int gi = tid >> 6, n = tid & 63;
    char* Gg = gi ? G1 : G0;
#pragma unroll
    for (int c = 20; c < 32; ++c) ast(Gg, n, c * 2, (_Float16)0.f);
#pragma unroll
    for (int c = 27; c < 32; ++c) ast(Gg, n, 64 + c * 2, (_Float16)0.f);
  }
  // ---- pos loads (2) ----
  const float* pp = data + base + (long)(wv >> 1) * 1728 + lane * 27;
  const float px = pp[0], py = pp[1];
  // ---- lidar param window (10) ----
  float bl1r[8];
#pragma unroll
  for (int t = 0; t < 8; ++t) bl1r[t] = b_l1[t * 16 + lc];
  float bl2r[2];
#pragma unroll
  for (int t = 0; t < 2; ++t) { const int c = t * 16 + lc; bl2r[t] = b_l2[c < 20 ? c : 19]; }

  lgkm0(); rbar();   // staged inputs visible

  // ---- adjacency mask (exact double cone + guard-band atan2 fallback) ----
  {
    const int g = wv >> 1;
    const float FOVF = (float)(0.35 * 3.14159265358979323846);
    const double TT = tan(0.35 * 3.14159265358979323846);
    const double T2 = TT * TT;
    for (int jj = 0; jj < 32; ++jj) {
      const int j = (wv & 1) * 32 + jj;
      const float x0j = __shfl(px, j, 64);
      const float x1j = __shfl(py, j, 64);
      const float dxf = px - x0j;
      const float dyf = py - x1j;
      const float dist = sqrtf(dxf * dxf + dyf * dyf);
      bool pred;
      if (lane == j || dist > 10.0f) {
        pred = false;
      } else if (dxf <= 0.0f) {
        pred = (dxf == 0.0f && dyf == 0.0f);
      } else {
        const double qa = (double)dyf * (double)dyf;
        const double qb = (double)dxf * (double)dxf * T2;
        if (qa <= qb * 0.99999) pred = true;
        else if (qa >= qb * 1.00001) pred = false;
        else pred = (fabsf((float)atan2((double)dyf, (double)dxf)) <= FOVF);
      }
      const u64 bal = __ballot(pred);
      if (lane == 0) sm.mcol[g][j] = bal | (1ull << j);
    }
  }

  // ---- lidar MLP ----
  h8 afl1_0 = ald8(G0, row0, kg * 16);
  h8 afl1_1 = ald8(G1, row0, kg * 16);
  h8 afl2_0[4], afl2_1[4];
  s_family<32, 27>(Wl1p, bl1r, &afl1_0, &afl1_1, afl2_0, afl2_1, S, wbase, wbi, tid,
      [&](int s, int bi) { stage32(Wl2p, s, wbase + bi * 4096, tid); });
  mm32_run<1>(Wl2p, bl2r, afl2_0, afl2_1, G0, G1, wbase, wbi, tid,
      [&](int s, int bi) { stage64(W11p, 32, 0, s, wbase + bi * 4096, tid); });
  lgkm0(); rbar();

  // ---- GIN layer 1 ----
  agg32_2g(sm.mcol[0], sm.mcol[1], G0, G1, tid);
  lgkm0(); rbar();
  float b11r[8];
#pragma unroll
  for (int t = 0; t < 8; ++t) b11r[t] = b11[t * 16 + lc];
  h8 af11_0 = ald8(G0, row0, kg * 16);
  h8 af11_1 = ald8(G1, row0, kg * 16);
  mm_run<32, true, false, true, 9>(W11p, b11r, &af11_0, &af11_1, G0, G1, wbase, wbi, tid,
      [&](int s, int bi) { stage64(W12p, 128, 0, s, wbase + bi * 4096, tid); });
  float b12r[8];
#pragma unroll
  for (int t = 0; t < 8; ++t) b12r[t] = b12[t * 16 + lc];
  h8 af12_0[4], af12_1[4];
#pragma unroll
  for (int i = 0; i < 4; ++i) {
    af12_0[i] = ald8(G0, row0, i * 64 + kg * 16);
    af12_1[i] = ald8(G1, row0, i * 64 + kg * 16);
  }
  mm_run<128, true, false, true, 9>(W12p, b12r, af12_0, af12_1, G0, G1, wbase, wbi, tid,
      [&](int s, int bi) { stage64(W21p, 128, 0, s, wbase + bi * 4096, tid); });
  lgkm0(); rbar();

  // ---- GIN layer 2: agg -> S halves -> W21 A-frags ----
  h8 af21_0[4], af21_1[4];
#pragma unroll
  for (int p = 0; p < 4; ++p) {
    const int oc = p >> 1, g = p & 1;
    if (p) rbar();
    agg128_half(sm.mcol[g], g ? G1 : G0, S, oc, tid);
    lgkm0(); rbar();
    h8* afd = g ? af21_1 : af21_0;
    afd[oc * 2 + 0] = sld8(S, row0, kg * 16);
    afd[oc * 2 + 1] = sld8(S, row0, 64 + kg * 16);
    lgkm0();
  }
  float b21r[8];
#pragma unroll
  for (int t = 0; t < 8; ++t) b21r[t] = b21[t * 16 + lc];
  mm_run<128, true, false, true, 9>(W21p, b21r, af21_0, af21_1, G0, G1, wbase, wbi, tid,
      [&](int s, int bi) { stage64(W22p, 128, 0, s, wbase + bi * 4096, tid); });
  float b22r[8];
#pragma unroll
  for (int t = 0; t < 8; ++t) b22r[t] = b22[t * 16 + lc];
  h8 af22_0[4], af22_1[4];
#pragma unroll
  for (int i = 0; i < 4; ++i) {
    af22_0[i] = ald8(G0, row0, i * 64 + kg * 16);
    af22_1[i] = ald8(G1, row0, i * 64 + kg * 16);
  }
  mm_run<128, true, false, true, 9>(W22p, b22r, af22_0, af22_1, G0, G1, wbase, wbi, tid,
      [&](int s, int bi) { stage64(Wat0, 128, 0, s, wbase + bi * 4096, tid); });

  // ---- transformer layer 0 ----
  float batr[8];
#pragma unroll
  for (int t = 0; t < 8; ++t) batr[t] = batp[t * 16 + lc];
  h8 afat_0[4], afat_1[4];
#pragma unroll
  for (int i = 0; i < 4; ++i) {
    afat_0[i] = ald8(G0, row0, i * 64 + kg * 16);
    afat_1[i] = ald8(G1, row0, i * 64 + kg * 16);
  }
  mm_run<128, false, true, true, 9>(Wat0, batr, afat_0, afat_1, G0, G1, wbase, wbi, tid,
      [&](int s, int bi) { stage64(Wf1_0, 128, s, 0, wbase + bi * 4096, tid); });
  {
    const int q = tid & 3;
    float4 g14[8], b14[8];
#pragma unroll
    for (int i = 0; i < 8; ++i) {
      g14[i] = *(const float4*)(ln1_g + q * 32 + i * 4);
      b14[i] = *(const float4*)(ln1_b + q * 32 + i * 4);
    }
    float bf1r[8];
#pragma unroll
    for (int t = 0; t < 8; ++t) bf1r[t] = bf1[t * 16 + lc];
    layer_norm(G0, g14, b14, tid);
    layer_norm(G1, g14, b14, tid);
    h8 afs0[4], afs1[4];
#pragma unroll
    for (int i = 0; i < 4; ++i) {
      afs0[i] = ald8(G0, row0, i * 64 + kg * 16);
      afs1[i] = ald8(G1, row0, i * 64 + kg * 16);
    }
    h8 aff2_0[4], aff2_1[4];
    s_family<128, 25>(Wf1_0, bf1r, afs0, afs1, aff2_0, aff2_1, S, wbase, wbi, tid,
        [&](int s, int bi) { stage64(Wf2_0, 128, 0, s, wbase + bi * 4096, tid); });
    float bf2r[8];
#pragma unroll
    for (int t = 0; t < 8; ++t) bf2r[t] = bf2[t * 16 + lc];
    mm_run<128, false, true, true, 9>(Wf2_0, bf2r, aff2_0, aff2_1, G0, G1, wbase, wbi, tid,
        [&](int s, int bi) { stage64(Wat1, 128, 0, s, wbase + bi * 4096, tid); });
  }
  // LN2(l=0) + AT1 window (counted into AT1's W0=25)
  {
    const int q = tid & 3;
    float4 g24[8], b24[8];
#pragma unroll
    for (int i = 0; i < 8; ++i) {
      g24[i] = *(const float4*)(ln2_g + q * 32 + i * 4);
      b24[i] = *(const float4*)(ln2_b + q * 32 + i * 4);
    }
    float bat1r[8];
#pragma unroll
    for (int t = 0; t < 8; ++t) bat1r[t] = batp[128 + t * 16 + lc];
    layer_norm(G0, g24, b24, tid);
    layer_norm(G1, g24, b24, tid);
    h8 afat1_0[4], afat1_1[4];
#pragma unroll
    for (int i = 0; i < 4; ++i) {
      afat1_0[i] = ald8(G0, row0, i * 64 + kg * 16);
      afat1_1[i] = ald8(G1, row0, i * 64 + kg * 16);
    }
    mm_run<128, false, true, true, 25>(Wat1, bat1r, afat1_0, afat1_1, G0, G1, wbase, wbi, tid,
        [&](int s, int bi) { stage64(Wf1_1, 128, s, 0, wbase + bi * 4096, tid); });
  }
  // ---- transformer layer 1 FF ----
  {
    const int q = tid & 3;
    float4 g14[8], b14[8];
#pragma unroll
    for (int i = 0; i < 8; ++i) {
      g14[i] = *(const float4*)(ln1_g + 128 + q * 32 + i * 4);
      b14[i] = *(const float4*)(ln1_b + 128 + q * 32 + i * 4);
    }
    float bf1r[8];
#pragma unroll
    for (int t = 0; t < 8; ++t) bf1r[t] = bf1[128 + t * 16 + lc];
    layer_norm(G0, g14, b14, tid);
    layer_norm(G1, g14, b14, tid);
    h8 afs0[4], afs1[4];
#pragma unroll
    for (int i = 0; i < 4; ++i) {
      afs0[i] = ald8(G0, row0, i * 64 + kg * 16);
      afs1[i] = ald8(G1, row0, i * 64 + kg * 16);
    }
    h8 aff2_0[4], aff2_1[4];
    s_family<128, 25>(Wf1_1, bf1r, afs0, afs1, aff2_0, aff2_1, S, wbase, wbi, tid,
        [&](int s, int bi) { stage64(Wf2_1, 128, 0, s, wbase + bi * 4096, tid); });
    float bf2r[8];
#pragma unroll
    for (int t = 0; t < 8; ++t) bf2r[t] = bf2[128 + t * 16 + lc];
    mm_run<128, false, true, false, 9>(Wf2_1, bf2r, aff2_0, aff2_1, G0, G1, wbase, wbi, tid,
        [&](int, int) {});
  }
  // final LN2 (l=1), plain loads (no counted waits after)
  {
    const int q = tid & 3;
    float4 g24[8], b24[8];
#pragma unroll
    for (int i = 0; i < 8; ++i) {
      g24[i] = *(const float4*)(ln2_g + 128 + q * 32 + i * 4);
      b24[i] = *(const float4*)(ln2_b + 128 + q * 32 + i * 4);
    }
    layer_norm(G0, g24, b24, tid);
    layer_norm(G1, g24, b24, tid);
  }

  // ---- head (wave-local rows) ----
#pragma unroll
  for (int g = 0; g < 2; ++g) {
    const char* Pg = g ? G1 : G0;
    const int n = tid >> 2, q = tid & 3;
    float s = 0.f;
#pragma unroll
    for (int u = 0; u < 4; ++u) {
      const h8 v = ald8(Pg, n, q * 64 + u * 16);
      const float4 w0 = *(const float4*)(Wfc + q * 32 + u * 8);
      const float4 w1 = *(const float4*)(Wfc + q * 32 + u * 8 + 4);
      s = fmaf((float)v[0], w0.x, s); s = fmaf((float)v[1], w0.y, s);
      s = fmaf((float)v[2], w0.z, s); s = fmaf((float)v[3], w0.w, s);
      s = fmaf((float)v[4], w1.x, s); s = fmaf((float)v[5], w1.y, s);
      s = fmaf((float)v[6], w1.z, s); s = fmaf((float)v[7], w1.w, s);
    }
    s += __shfl_xor(s, 1, 64);
    s += __shfl_xor(s, 2, 64);
    if (q == 0) out[((long)b * 2 + g) * NN + n] = s + bfc[0];
  }
}

extern "C" void kernel_launch(void* const* d_in, const int* in_sizes, int n_in,
                              void* d_out, int out_size, void* d_ws, size_t ws_size,
                              hipStream_t stream) {
  const float* data  = (const float*)d_in[0];
  const float* W_l1  = (const float*)d_in[1];
  const float* b_l1  = (const float*)d_in[2];
  const float* W_l2  = (const float*)d_in[3];
  const float* b_l2  = (const float*)d_in[4];
  const float* W11   = (const float*)d_in[5];
  const float* b11   = (const float*)d_in[6];
  const float* W12   = (const float*)d_in[7];
  const float* b12   = (const float*)d_in[8];
  const float* W21   = (const float*)d_in[9];
  const float* b21   = (const float*)d_in[10];
  const float* W22   = (const float*)d_in[11];
  const float* b22   = (const float*)d_in[12];
  const float* Wqkv  = (const float*)d_in[13];
  const float* bqkv  = (const float*)d_in[14];
  const float* Wo    = (const float*)d_in[15];
  const float* bo    = (const float*)d_in[16];
  const float* ln1_g = (const float*)d_in[17];
  const float* ln1_b = (const float*)d_in[18];
  const float* Wf1   = (const float*)d_in[19];
  const float* bf1   = (const float*)d_in[20];
  const float* Wf2   = (const float*)d_in[21];
  const float* bf2   = (const float*)d_in[22];
  const float* ln2_g = (const float*)d_in[23];
  const float* ln2_b = (const float*)d_in[24];
  const float* Wfc   = (const float*)d_in[25];
  const float* bfc   = (const float*)d_in[26];

  _Float16* ws = (_Float16*)d_ws;

  prepA<<<dim3(624), dim3(256), 0, stream>>>(
      W_l1, W_l2, W11, W12, W21, W22, Wf1, Wf2, ws);
  prepB<<<dim3(129), dim3(256), 0, stream>>>(Wqkv, bqkv, Wo, bo, ws);

  gin_critic_kernel<<<dim3(NB / 2), dim3(256), 0, stream>>>(
      data, b_l1, b_l2, b11, b12, b21, b22,
      ln1_g, ln1_b, bf1, bf2, ln2_g, ln2_b, Wfc, bfc,
      ws, (float*)d_out);
}